// Round 1
// 227.079 us; speedup vs baseline: 1.0167x; 1.0167x over previous
//
#include <hip/hip_runtime.h>

#define HW    512
#define OUTW  128
#define NIMG  96                          // 32*3
#define N_HR  ((long long)NIMG*HW*HW)     // 25165824
#define N_LR  ((long long)NIMG*OUTW*OUTW) // 1572864
#define NPART (NIMG*32)                   // one slot per wave (4 out rows each)

// PyTorch bicubic kernel, a = -0.75
__device__ __forceinline__ float cubic075(float x){
    float ax = fabsf(x);
    float ax2 = ax*ax, ax3 = ax2*ax;
    const float A = -0.75f;
    float f1 = (A+2.f)*ax3 - (A+3.f)*ax2 + 1.f;
    float f2 = A*ax3 - 5.f*A*ax2 + 8.f*A*ax - 4.f*A;
    return ax <= 1.f ? f1 : (ax < 2.f ? f2 : 0.f);
}

// scale=4 antialiased window: 16 taps, dist=(k-7.5)/4, normalized.
// Shift-invariant across all output positions (verified absmax=0.0 earlier).
__device__ __forceinline__ void get_weights(float w[16]){
    float s = 0.f;
#pragma unroll
    for (int k = 0; k < 16; ++k){
        float d = ((float)k - 7.5f) * 0.25f;
        w[k] = cubic075(d);
        s += w[k];
    }
#pragma unroll
    for (int k = 0; k < 16; ++k) w[k] /= s;
}

// Fully fused, barrier-free. One WAVE = (img, 4 consecutive output rows).
// R3 restructure: the 28-row loop is split into three fully-unrolled phases
// (prolog 0..5 / steady 6..21 / epilog 22..27) so EVERY global load is
// unconditional at compile time. This lets the compiler emit counted
// s_waitcnt vmcnt(N) instead of conservative drains at branch merges
// (the prior depth-2 rotating pipeline guarded its prefetches with runtime
// branches -> path-dependent outstanding-load counts -> vmcnt(0)-style
// waits every iteration -> latency-serialized at 14% VALUBusy).
// Prefetch distance is now 4 rows (ring-4, all indices compile-time).
__global__ __launch_bounds__(256) void kmain(const float* __restrict__ pred,
                                             const float* __restrict__ tgt,
                                             const float* __restrict__ lr,
                                             double* __restrict__ part){
    const int img = blockIdx.x >> 3;
    const int tid = threadIdx.x;
    const int w   = tid >> 6;                 // wave in block 0..3
    const int l   = tid & 63;
    const int gw  = ((blockIdx.x & 7) << 2) + w;  // wave in image 0..31
    const int o0  = gw << 2;                  // first output row
    const int s   = (gw << 4) - 6;            // first (unclamped) input row
    const int li  = 2*l;

    float wt[16]; get_weights(wt);
    const float* P = pred + (size_t)img * (HW*HW);
    const float* T = tgt  + (size_t)img * (HW*HW);
    const float* L = lr   + (size_t)img * (OUTW*OUTW);

    float acc[4][2] = {{0.f,0.f},{0.f,0.f},{0.f,0.f},{0.f,0.f}};
    float pix_acc = 0.f, lr_acc = 0.f;

    float4 p[4][2];   // pred ring buffer, prefetch distance 4
    float4 t[4][2];   // tgt ring buffer (valid for rows 6..21 only)

#define PREDROW(i) ((const float4*)(P + (size_t)min(HW-1, max(0, s+(i)))*HW))
#define TGTROW(i)  ((const float4*)(T + (size_t)(s+(i))*HW))
#define ISSUE_P(i) do{ const float4* _rp = PREDROW(i); \
                       p[(i)&3][0]=_rp[li]; p[(i)&3][1]=_rp[li+1]; }while(0)
#define ISSUE_T(i) do{ const float4* _tp = TGTROW(i); \
                       t[(i)&3][0]=_tp[li]; t[(i)&3][1]=_tp[li+1]; }while(0)

#define CONSUME(i, DOPIX) do{                                                   \
    const float4 c0 = p[(i)&3][0], c1 = p[(i)&3][1];                            \
    const float p0=c0.x,p1v=c0.y,p2v=c0.z,p3=c0.w,                              \
                p4=c1.x,p5=c1.y,p6=c1.z,p7=c1.w;                                \
    if (DOPIX){                                                                 \
        const float4 t0 = t[(i)&3][0], t1 = t[(i)&3][1];                        \
        pix_acc += fabsf(p0-t0.x)+fabsf(p1v-t0.y)+fabsf(p2v-t0.z)+fabsf(p3-t0.w)\
                 + fabsf(p4-t1.x)+fabsf(p5-t1.y)+fabsf(p6-t1.z)+fabsf(p7-t1.w); \
    }                                                                           \
    float Lm6 = __shfl_up(p2v,1,64), Lm5 = __shfl_up(p3,1,64),                  \
          Lm4 = __shfl_up(p4,1,64),  Lm3 = __shfl_up(p5,1,64),                  \
          Lm2 = __shfl_up(p6,1,64),  Lm1 = __shfl_up(p7,1,64);                  \
    float R8  = __shfl_down(p0,1,64), R9  = __shfl_down(p1v,1,64),              \
          R10 = __shfl_down(p2v,1,64),R11 = __shfl_down(p3,1,64),               \
          R12 = __shfl_down(p4,1,64), R13 = __shfl_down(p5,1,64);               \
    if (l == 0){ Lm6=p0; Lm5=p0; Lm4=p0; Lm3=p0; Lm2=p0; Lm1=p0; }              \
    if (l == 63){ R8=p7; R9=p7; R10=p7; R11=p7; R12=p7; R13=p7; }               \
    float w20[20] = {Lm6,Lm5,Lm4,Lm3,Lm2,Lm1,p0,p1v,p2v,p3,p4,p5,p6,p7,         \
                     R8,R9,R10,R11,R12,R13};                                    \
    float h0 = 0.f, h1 = 0.f;                                                   \
    _Pragma("unroll")                                                           \
    for (int k = 0; k < 16; ++k){ h0 += wt[k]*w20[k]; h1 += wt[k]*w20[k+4]; }   \
    _Pragma("unroll")                                                           \
    for (int q = 0; q < 4; ++q){                                                \
        int kk = (i) - 4*q;                                                     \
        if (kk >= 0 && kk < 16){ acc[q][0] += wt[kk]*h0; acc[q][1] += wt[kk]*h1; } \
    }                                                                           \
}while(0)

    // prime the pred pipeline: rows 0..3 in flight
    ISSUE_P(0); ISSUE_P(1); ISSUE_P(2); ISSUE_P(3);

#pragma unroll
    for (int i = 0; i < 6; ++i){          // prolog: bottom halo rows
        CONSUME(i, false);
        ISSUE_P(i+4);                     // rows 4..9 (clamped)
        if (i+4 >= 6) ISSUE_T(i+4);       // folds per unrolled body
    }
#pragma unroll
    for (int i = 6; i < 22; ++i){         // steady state: pix + resize
        CONSUME(i, true);                 // rows s+6..s+21 always in-bounds
        ISSUE_P(i+4);                     // rows 10..25 (clamp handles top)
        if (i+4 < 22) ISSUE_T(i+4);       // folds per unrolled body
    }
#pragma unroll
    for (int i = 22; i < 28; ++i){        // epilog: top halo rows
        CONSUME(i, false);
        if (i+4 < 28) ISSUE_P(i+4);       // rows 26,27 only; folds
    }

#undef CONSUME
#undef ISSUE_T
#undef ISSUE_P
#undef TGTROW
#undef PREDROW

    // lr term: lane l holds out cols 2l,2l+1 for rows o0..o0+3
#pragma unroll
    for (int q = 0; q < 4; ++q){
        const float2 lv = *(const float2*)(L + (size_t)(o0+q)*OUTW + li);
        lr_acc += fabsf(acc[q][0]-lv.x) + fabsf(acc[q][1]-lv.y);
    }

    // intra-wave reduction, one slot per wave (no atomics, no init needed)
#pragma unroll
    for (int off = 32; off > 0; off >>= 1){
        pix_acc += __shfl_down(pix_acc, off, 64);
        lr_acc  += __shfl_down(lr_acc,  off, 64);
    }
    if (l == 0){
        const int slot = (blockIdx.x << 2) + w;
        part[slot]         = (double)pix_acc;
        part[NPART + slot] = (double)lr_acc;
    }
}

__global__ __launch_bounds__(256) void k3(const double* __restrict__ part,
                                          float* __restrict__ out){
    const int t = threadIdx.x;
    double v1 = 0.0, v2 = 0.0;
    for (int i = t; i < NPART; i += 256){
        v1 += part[i];
        v2 += part[NPART + i];
    }
#pragma unroll
    for (int off = 32; off > 0; off >>= 1){
        v1 += __shfl_down(v1, off, 64);
        v2 += __shfl_down(v2, off, 64);
    }
    __shared__ double s1[4], s2[4];
    const int lane = t & 63, wid = t >> 6;
    if (lane == 0){ s1[wid] = v1; s2[wid] = v2; }
    __syncthreads();
    if (t == 0){
        double S1 = s1[0]+s1[1]+s1[2]+s1[3];
        double S2 = s2[0]+s2[1]+s2[2]+s2[3];
        float pix     = (float)(S1 / (double)N_HR);
        float lr_term = (float)(S2 / (double)N_LR);
        float pair    = 0.f;
        float consist = 1.0f * lr_term + 1.0f * pair;   // LAM_LR, LAM_PAIR
        float total   = pix + 0.1f * consist;           // LAM_CONSIST
        out[0] = total; out[1] = pix; out[2] = consist; out[3] = lr_term; out[4] = pair;
    }
}

extern "C" void kernel_launch(void* const* d_in, const int* in_sizes, int n_in,
                              void* d_out, int out_size, void* d_ws, size_t ws_size,
                              hipStream_t stream){
    const float* pred = (const float*)d_in[0];
    const float* tgt  = (const float*)d_in[1];
    const float* lrr  = (const float*)d_in[2];
    float* out = (float*)d_out;

    double* part = (double*)d_ws;   // 2 * 3072 doubles = 48 KB, every slot written

    kmain<<<NIMG*8, 256, 0, stream>>>(pred, tgt, lrr, part);
    k3<<<1, 256, 0, stream>>>(part, out);
}